// Round 13
// baseline (849.630 us; speedup 1.0000x reference)
//
#include <hip/hip_runtime.h>

// out[b,n,f] = sum_{l,m} x1[b,l,f] * x2[b,m,f] * cg[l,m,n]
// B=50000, d1=d2=9, d3=25, MUL=512, fp32 in/out.
//
// MFMA formulation: per b, out[n,f] = sum_k W[k,n]*S[k,f], k=(l,m) pad 96;
// S=x1*x2 bf16 in LDS (row per f-channel, pitch 208B = 13x16B, 2-way bank
// alias = free); W=cg bf16 regs; mfma_f32_16x16x32_bf16 fp32-accum.
// No barriers: wave wv's threads (tid 64wv..64wv+63) write exactly the S
// rows its MFMA reads; per-wave DS ops are in program order.
//
// Ledger: R7 858 (chunked, 12w/CU) | R8 874 (L2 st) | R9 885 (2-deep pf)
// | R10 831 (transpose epi) | R11 843 (full-row, 4w/CU) | R12 831 (packed
// f32x4 st == R10 -> store width exonerated). All levers <=3%; 5.3 TB/s.
// R13 (final cell): 512-thread block = full-row contiguity AT 8 waves/CU;
// 5000 blocks (half the prologues); each 2KB out-row written by one block.
// Pre-commit: >=805us -> declare roofline (4.4GB mandatory @ mixed-stream
// ~5.5-6.3 TB/s => 700-800us floor).

#define BATCH 50000
#define MUL   512
#define D3    25
#define ROWB  208
#define RPB   10
#define SMEM_BYTES (512 * ROWB)   // 106496 B

typedef __bf16 bf16x8 __attribute__((ext_vector_type(8)));
typedef float  f32x4  __attribute__((ext_vector_type(4)));

__global__ void __launch_bounds__(512) tp_kernel(
    const float* __restrict__ x1,
    const float* __restrict__ x2,
    const float* __restrict__ cg,
    float* __restrict__ out) {

    extern __shared__ char smem[];

    const int tid  = threadIdx.x;
    const int lane = tid & 63;
    const int wv   = tid >> 6;            // 8 waves
    const int b0   = blockIdx.x * RPB;

    // ---- W fragments once per block (cg 8KB, L2-hot after first blocks) ----
    // A[mt][ks]: row n = 16*mt + (lane&15), k = 32*ks + 8*(lane>>4) + j
    bf16x8 afrag[2][3];
    #pragma unroll
    for (int mt = 0; mt < 2; ++mt) {
        const int n = 16 * mt + (lane & 15);
        #pragma unroll
        for (int ks = 0; ks < 3; ++ks) {
            #pragma unroll
            for (int j = 0; j < 8; ++j) {
                const int k = 32 * ks + 8 * (lane >> 4) + j;
                float w = (k < 81 && n < D3) ? cg[k * D3 + n] : 0.0f;
                afrag[mt][ks][j] = (__bf16)w;
            }
        }
    }

    const float* x1p = x1 + (size_t)b0 * (9 * MUL) + tid;  // full 512-row
    const float* x2p = x2 + (size_t)b0 * (9 * MUL) + tid;
    // per-wave output base: row n=0, f = wv*64
    float* op = out + (size_t)b0 * (D3 * MUL) + wv * 64;

    float a[9], c[9];
    #pragma unroll
    for (int l = 0; l < 9; ++l) a[l] = x1p[l * MUL];
    #pragma unroll
    for (int m = 0; m < 9; ++m) c[m] = x2p[m * MUL];

    uint4* row = reinterpret_cast<uint4*>(smem + (size_t)tid * ROWB);
    const char* bbase0 = smem + (size_t)(wv * 64 + (lane & 15)) * ROWB
                              + (lane >> 4) * 16;
    // wave's private LDS region (13312B), reused as fp32 tile [25][64]
    float* twave = reinterpret_cast<float*>(smem + (size_t)wv * 64 * ROWB);

    for (int r = 0; r < RPB; ++r) {
        // ---- S products (row r) -> bf16 -> own LDS row (96 k + pad) ----
        #pragma unroll
        for (int ch = 0; ch < 12; ++ch) {
            bf16x8 v;
            #pragma unroll
            for (int j = 0; j < 8; ++j) {
                const int k = ch * 8 + j;
                const float p = (k < 81) ? a[k / 9] * c[k % 9] : 0.0f;
                v[j] = (__bf16)p;
            }
            row[ch] = __builtin_bit_cast(uint4, v);
        }

        // ---- prefetch next row's x (latency hides under MFMA below) ----
        x1p += 9 * MUL;
        x2p += 9 * MUL;
        if (r != RPB - 1) {
            #pragma unroll
            for (int l = 0; l < 9; ++l) a[l] = x1p[l * MUL];
            #pragma unroll
            for (int m = 0; m < 9; ++m) c[m] = x2p[m * MUL];
        }

        // ---- B fragments from own rows, MFMA ----
        f32x4 acc[2][4];
        #pragma unroll
        for (int mt = 0; mt < 2; ++mt)
            #pragma unroll
            for (int ft = 0; ft < 4; ++ft)
                acc[mt][ft] = (f32x4){0.f, 0.f, 0.f, 0.f};

        #pragma unroll
        for (int ft = 0; ft < 4; ++ft) {
            const char* bb = bbase0 + ft * 16 * ROWB;
            #pragma unroll
            for (int ks = 0; ks < 3; ++ks) {
                bf16x8 bfrag = *reinterpret_cast<const bf16x8*>(bb + ks * 64);
                acc[0][ft] = __builtin_amdgcn_mfma_f32_16x16x32_bf16(
                    afrag[0][ks], bfrag, acc[0][ft], 0, 0, 0);
                acc[1][ft] = __builtin_amdgcn_mfma_f32_16x16x32_bf16(
                    afrag[1][ks], bfrag, acc[1][ft], 0, 0, 0);
            }
        }

        // ---- epilogue A: acc -> wave's LDS tile [n][f_local] (S is dead) ----
        #pragma unroll
        for (int mt = 0; mt < 2; ++mt) {
            #pragma unroll
            for (int rr = 0; rr < 4; ++rr) {
                const int n = 16 * mt + (lane >> 4) * 4 + rr;
                if (n < D3) {
                    #pragma unroll
                    for (int ft = 0; ft < 4; ++ft)
                        twave[n * 64 + ft * 16 + (lane & 15)] = acc[mt][ft][rr];
                }
            }
        }

        // ---- epilogue B: packed f32x4 NT stores (25 rows x 16 quads) ----
        #pragma unroll
        for (int idx = 0; idx < 7; ++idx) {
            const int p = idx * 64 + lane;        // 400 quads per wave
            if (p < D3 * 16) {
                const int n = p >> 4;
                const int q = p & 15;
                const f32x4 v = *reinterpret_cast<const f32x4*>(
                    twave + n * 64 + q * 4);
                __builtin_nontemporal_store(
                    v, reinterpret_cast<f32x4*>(op + (size_t)n * MUL + q * 4));
            }
        }
        op += D3 * MUL;
    }
}

extern "C" void kernel_launch(void* const* d_in, const int* in_sizes, int n_in,
                              void* d_out, int out_size, void* d_ws, size_t ws_size,
                              hipStream_t stream) {
    const float* x1 = (const float*)d_in[0];
    const float* x2 = (const float*)d_in[1];
    const float* cg = (const float*)d_in[2];
    float* out = (float*)d_out;

    // allow >64KB dynamic LDS (gfx950: 160KB/CU); host-side, idempotent,
    // graph-capture safe
    hipFuncSetAttribute(reinterpret_cast<const void*>(tp_kernel),
                        hipFuncAttributeMaxDynamicSharedMemorySize, SMEM_BYTES);

    dim3 grid(BATCH / RPB);
    dim3 block(512);
    tp_kernel<<<grid, block, SMEM_BYTES, stream>>>(x1, x2, cg, out);
}